// Round 7
// baseline (327.311 us; speedup 1.0000x reference)
//
#include <hip/hip_runtime.h>

typedef __attribute__((ext_vector_type(8))) __bf16 bf16x8;
typedef __attribute__((ext_vector_type(4))) float f32x4;
typedef __attribute__((ext_vector_type(8))) unsigned short ushortx8;

__device__ inline unsigned short f2bf(float f) {
  unsigned int u = __float_as_uint(f);
  unsigned int r = (u + 0x7FFFu + ((u >> 16) & 1u)) >> 16;  // RNE
  return (unsigned short)r;
}

// ---------------- prep: fused conv | tconv | detect (block-range dispatch) ----------------
__global__ __launch_bounds__(256) void prep_kernel(const float* __restrict__ x,
                                                   unsigned short* __restrict__ xb, int total8,
                                                   const float* __restrict__ bases,
                                                   unsigned short* __restrict__ bmt,
                                                   const unsigned char* __restrict__ mask,
                                                   int mbytes, int* __restrict__ flag_out,
                                                   int CB, int TB) {
  int bid = blockIdx.x;
  if (bid < CB) {
    int id = bid * 256 + threadIdx.x;
    if (id >= total8) return;
    f32x4 f0 = ((const f32x4*)x)[2 * id];
    f32x4 f1 = ((const f32x4*)x)[2 * id + 1];
    ushortx8 r;
    r[0] = f2bf(f0[0]); r[1] = f2bf(f0[1]); r[2] = f2bf(f0[2]); r[3] = f2bf(f0[3]);
    r[4] = f2bf(f1[0]); r[5] = f2bf(f1[1]); r[6] = f2bf(f1[2]); r[7] = f2bf(f1[3]);
    ((ushortx8*)xb)[id] = r;
  } else if (bid < CB + TB) {
    int id = (bid - CB) * 256 + threadIdx.x;
    if (id >= 128 * 1024) return;
    int o = id >> 10, k = id & 1023, b = k >> 7, d = k & 127;
    bmt[id] = f2bf(bases[b * 16384 + d * 128 + o]);
  } else {
    __shared__ int nz_off, big;
    if (threadIdx.x == 0) { nz_off = 0; big = 0; }
    __syncthreads();
    int lnz = 0, lbig = 0;
    for (int i = threadIdx.x; i < mbytes; i += 256) {
      unsigned char v = mask[i];
      if ((i & 3) && v) lnz++;
      if (v > 1) lbig++;
    }
    if (lnz) atomicAdd(&nz_off, lnz);
    if (lbig) atomicAdd(&big, lbig);
    __syncthreads();
    if (threadIdx.x == 0) *flag_out = (nz_off == 0) ? 0 : ((big == 0) ? 1 : 2);
  }
}

// ---------------- S1: histogram over target nodes (both directions) ----------------
__global__ __launch_bounds__(256) void hist_kernel(const int* __restrict__ src,
                                                   const int* __restrict__ tgt, int E,
                                                   int* __restrict__ cnt) {
  int i = blockIdx.x * 256 + threadIdx.x;
  if (i >= E) return;
  atomicAdd(&cnt[tgt[i]], 1);
  atomicAdd(&cnt[src[i]], 1);
}

// ---------------- S2a: per-block sums ----------------
__global__ __launch_bounds__(256) void scan1_kernel(const int* __restrict__ cnt, int N,
                                                    int* __restrict__ bsum) {
  __shared__ int s[256];
  int t = threadIdx.x, i = blockIdx.x * 256 + t;
  s[t] = (i < N) ? cnt[i] : 0;
  __syncthreads();
#pragma unroll
  for (int off = 128; off > 0; off >>= 1) {
    if (t < off) s[t] += s[t + off];
    __syncthreads();
  }
  if (t == 0) bsum[blockIdx.x] = s[0];
}

// ---------------- S2b: scan block sums (nb <= 512) ----------------
__global__ void scan2_kernel(const int* __restrict__ bsum, int nb,
                             int* __restrict__ bexcl, int* __restrict__ base, int N) {
  __shared__ int s[512];
  int t = threadIdx.x;
  int v = (t < nb) ? bsum[t] : 0;
  s[t] = v;
  __syncthreads();
  for (int off = 1; off < 512; off <<= 1) {
    int x = (t >= off) ? s[t - off] : 0;
    __syncthreads();
    s[t] += x;
    __syncthreads();
  }
  if (t < nb) bexcl[t] = s[t] - v;
  if (t == nb - 1) base[N] = s[t];
}

// ---------------- S2c: per-element exclusive base + cursor ----------------
__global__ __launch_bounds__(256) void scan3_kernel(const int* __restrict__ cnt, int N,
                                                    const int* __restrict__ bexcl,
                                                    int* __restrict__ base,
                                                    int* __restrict__ cursor) {
  __shared__ int s[256];
  int t = threadIdx.x, i = blockIdx.x * 256 + t;
  int c = (i < N) ? cnt[i] : 0;
  s[t] = c;
  __syncthreads();
  for (int off = 1; off < 256; off <<= 1) {
    int x = (t >= off) ? s[t - off] : 0;
    __syncthreads();
    s[t] += x;
    __syncthreads();
  }
  if (i < N) {
    int v = bexcl[blockIdx.x] + s[t] - c;
    base[i] = v;
    cursor[i] = v;
  }
}

// ---------------- S3: scatter messages (src|rel, w) into target-sorted array ----------------
__global__ __launch_bounds__(256) void scatter_kernel(const int* __restrict__ src,
                                                      const int* __restrict__ tgt,
                                                      const int* __restrict__ et,
                                                      const float* __restrict__ ew, int E,
                                                      int* __restrict__ cursor,
                                                      uint2* __restrict__ msrw) {
  int i = blockIdx.x * 256 + threadIdx.x;
  if (i >= E) return;
  int s = src[i], g = tgt[i], r = et[i];
  unsigned wbits = __float_as_uint(ew[i]);
  int s1 = atomicAdd(&cursor[g], 1);
  msrw[s1] = make_uint2((unsigned)s | ((unsigned)r << 24), wbits);
  int s2 = atomicAdd(&cursor[s], 1);
  msrw[s2] = make_uint2((unsigned)g | ((unsigned)r << 24), wbits);
}

// ---------------- K: per-target gather (scalar meta, 8-deep MLP) + block MFMA ----------------
// block = 1024 thr (16 waves), owns 32 target rows; wave owns 2 targets.
// Message meta via SGPR (s_load) — no shfl, no LDS in the chain.
// LDS: zs = 32 rows x 1024 k bf16 (XOR-swizzled) = 65536 B
__global__ __launch_bounds__(1024, 8) void gather_kernel(
    const unsigned* __restrict__ xb32, const unsigned short* __restrict__ bmt,
    const int* __restrict__ base, const uint2* __restrict__ msrw,
    const float* __restrict__ rbw, const void* __restrict__ maskp,
    const int* __restrict__ flag_p, float* __restrict__ out, int N) {
  extern __shared__ char smem[];
  int t = threadIdx.x;
  int wid = t >> 6, l = t & 63;
  int t0 = blockIdx.x * 32;
  int flag = *flag_p;  // uniform

  for (int j = 0; j < 2; ++j) {
    int tg = __builtin_amdgcn_readfirstlane(t0 + wid * 2 + j);  // force SGPR
    int tgc = min(tg, N - 1);
    int beg = __builtin_amdgcn_readfirstlane(base[tgc]);
    int cnt = __builtin_amdgcn_readfirstlane(base[tgc + 1]) - beg;
    if (tg >= N) cnt = 0;
    // self-loop seed
    unsigned xs = xb32[(size_t)tgc * 64 + l];
    int keep;
    if (flag == 0)      keep = ((const int*)maskp)[tgc] != 0;
    else if (flag == 1) keep = ((const unsigned char*)maskp)[tgc] != 0;
    else                keep = ((const float*)maskp)[tgc] != 0.f;
    float ms = (keep && tg < N) ? 1.f : 0.f;
    float slo = __uint_as_float(xs << 16);
    float shi = __uint_as_float(xs & 0xFFFF0000u);
    float zlo[8], zhi[8];
#pragma unroll
    for (int b = 0; b < 8; ++b) {
      float a = ms * rbw[256 + b];  // uniform scalar load
      zlo[b] = a * slo;
      zhi[b] = a * shi;
    }
    for (int mb = 0; mb < cnt; mb += 8) {
      unsigned rowv[8];
      float wv[8];
      int relv[8];
      // meta: 8 independent scalar loads (msrw padded by 16 entries)
#pragma unroll
      for (int s = 0; s < 8; ++s) {
        int m = mb + s;
        uint2 mm = msrw[beg + m];
        int valid = m < cnt;                 // wave-uniform
        unsigned mx = valid ? mm.x : 0u;
        rowv[s] = mx & 0xFFFFFFu;
        relv[s] = (int)(mx >> 24);
        wv[s] = valid ? __uint_as_float(mm.y) : 0.f;
      }
      // 8 independent x-row loads (SGPR base + lane offset)
      unsigned xr[8];
#pragma unroll
      for (int s = 0; s < 8; ++s) xr[s] = xb32[(size_t)rowv[s] * 64 + l];
      // FMA
#pragma unroll
      for (int s = 0; s < 8; ++s) {
        const float* cc = rbw + relv[s] * 8;  // uniform scalar loads
        float lo = __uint_as_float(xr[s] << 16);
        float hi = __uint_as_float(xr[s] & 0xFFFF0000u);
        float w = wv[s];
#pragma unroll
        for (int b = 0; b < 8; ++b) {
          float a = w * cc[b];
          zlo[b] = fmaf(a, lo, zlo[b]);
          zhi[b] = fmaf(a, hi, zhi[b]);
        }
      }
    }
    // flush z row to LDS (bf16, XOR swizzle)
    int row = wid * 2 + j;
#pragma unroll
    for (int b = 0; b < 8; ++b) {
      unsigned pk = (unsigned)f2bf(zlo[b]) | ((unsigned)f2bf(zhi[b]) << 16);
      int byte = row * 2048 + ((b * 256 + l * 4) ^ ((row & 7) << 4));
      *(unsigned*)(smem + byte) = pk;
    }
  }
  __syncthreads();

  // MFMA: out[32 x 128] = Z(32 x 1024) @ Bstack(1024 x 128)
  // wave wid: row-tile rt = wid>>3 (x16), col-tile c8 = wid&7 (x16)
  int l15 = l & 15, lk8 = (l >> 4) * 8;
  int rt = wid >> 3, c8 = wid & 7;
  f32x4 acc = {};
  for (int ks = 0; ks < 32; ++ks) {
    int k0 = ks * 32 + lk8;
    int tr = rt * 16 + l15;
    bf16x8 a = *(const bf16x8*)(smem + tr * 2048 + ((k0 * 2) ^ ((tr & 7) << 4)));
    bf16x8 bb = *(const bf16x8*)(bmt + (size_t)(c8 * 16 + l15) * 1024 + k0);
    acc = __builtin_amdgcn_mfma_f32_16x16x32_bf16(a, bb, acc, 0, 0, 0);
  }
  int rowb = t0 + rt * 16 + (l >> 4) * 4;
  int col = c8 * 16 + l15;
#pragma unroll
  for (int i = 0; i < 4; ++i) {
    int row = rowb + i;
    if (row < N) out[(size_t)row * 128 + col] = acc[i];
  }
}

extern "C" void kernel_launch(void* const* d_in, const int* in_sizes, int n_in,
                              void* d_out, int out_size, void* d_ws, size_t ws_size,
                              hipStream_t stream) {
  const float* x = (const float*)d_in[0];
  const void* mask = d_in[1];
  const int* source = (const int*)d_in[2];
  const int* target = (const int*)d_in[3];
  const int* etype = (const int*)d_in[4];
  const float* eweight = (const float*)d_in[5];
  const float* bases = (const float*)d_in[6];
  const float* rbw = (const float*)d_in[7];
  float* out = (float*)d_out;

  const int N = in_sizes[1];   // mask element count == num nodes
  const int E = in_sizes[2];
  const int M = 2 * E;
  const int NB = (N + 255) / 256;

  // workspace layout (256B aligned)
  char* ws = (char*)d_ws;
  size_t off = 0;
  unsigned short* xb = (unsigned short*)(ws + off); off += (size_t)N * 256;        // bf16 x
  unsigned short* bmt = (unsigned short*)(ws + off); off += 128 * 1024 * 2;        // BmatT
  uint2* msrw = (uint2*)(ws + off); off += (size_t)(M + 16) * 8;                   // (src|rel, w)
  int* base = (int*)(ws + off); off += ((size_t)N + 64) * 4;                       // N+1 scan
  int* cursor = (int*)(ws + off); off += ((size_t)N + 64) * 4;
  int* cnt = (int*)(ws + off); off += ((size_t)N + 64) * 4;
  int* bsum = (int*)(ws + off); off += 2048;
  int* bexcl = (int*)(ws + off); off += 2048;
  int* flag = (int*)(ws + off); off += 256;

  hipMemsetAsync(cnt, 0, (size_t)N * 4, stream);
  int total8 = (N * 128) / 8;
  int CB = (total8 + 255) / 256;
  int TB = (128 * 1024 + 255) / 256;
  prep_kernel<<<CB + TB + 1, 256, 0, stream>>>(x, xb, total8, bases, bmt,
                                               (const unsigned char*)mask,
                                               N < 8192 ? N : 8192, flag, CB, TB);
  hist_kernel<<<(E + 255) / 256, 256, 0, stream>>>(source, target, E, cnt);
  scan1_kernel<<<NB, 256, 0, stream>>>(cnt, N, bsum);
  scan2_kernel<<<1, 512, 0, stream>>>(bsum, NB, bexcl, base, N);
  scan3_kernel<<<NB, 256, 0, stream>>>(cnt, N, bexcl, base, cursor);
  scatter_kernel<<<(E + 255) / 256, 256, 0, stream>>>(source, target, etype, eweight, E,
                                                      cursor, msrw);
  int gblk = (N + 31) / 32;
  size_t shmem = 65536;
  gather_kernel<<<gblk, 1024, shmem, stream>>>((const unsigned*)xb, bmt, base, msrw,
                                               rbw, mask, flag, out, N);
}

// Round 9
// 249.918 us; speedup vs baseline: 1.3097x; 1.3097x over previous
//
#include <hip/hip_runtime.h>

typedef __attribute__((ext_vector_type(8))) __bf16 bf16x8;
typedef __attribute__((ext_vector_type(4))) float f32x4;
typedef __attribute__((ext_vector_type(2))) float f32x2;
typedef __attribute__((ext_vector_type(8))) unsigned short ushortx8;

__device__ inline unsigned short f2bf(float f) {
  unsigned int u = __float_as_uint(f);
  unsigned int r = (u + 0x7FFFu + ((u >> 16) & 1u)) >> 16;  // RNE
  return (unsigned short)r;
}

// ---------------- prep: fused conv | tconv | hist | detect (block-range dispatch) ----------------
__global__ __launch_bounds__(256) void prep_kernel(const float* __restrict__ x,
                                                   unsigned short* __restrict__ xb, int total8,
                                                   const float* __restrict__ bases,
                                                   unsigned short* __restrict__ bmt,
                                                   const int* __restrict__ src,
                                                   const int* __restrict__ tgt, int E,
                                                   int* __restrict__ cnt,
                                                   const unsigned char* __restrict__ mask,
                                                   int mbytes, int* __restrict__ flag_out,
                                                   int CB, int TB, int HB) {
  int bid = blockIdx.x;
  if (bid < CB) {
    int id = bid * 256 + threadIdx.x;
    if (id >= total8) return;
    f32x4 f0 = ((const f32x4*)x)[2 * id];
    f32x4 f1 = ((const f32x4*)x)[2 * id + 1];
    ushortx8 r;
    r[0] = f2bf(f0[0]); r[1] = f2bf(f0[1]); r[2] = f2bf(f0[2]); r[3] = f2bf(f0[3]);
    r[4] = f2bf(f1[0]); r[5] = f2bf(f1[1]); r[6] = f2bf(f1[2]); r[7] = f2bf(f1[3]);
    ((ushortx8*)xb)[id] = r;
  } else if (bid < CB + TB) {
    int id = (bid - CB) * 256 + threadIdx.x;
    if (id >= 128 * 1024) return;
    int o = id >> 10, k = id & 1023, b = k >> 7, d = k & 127;
    bmt[id] = f2bf(bases[b * 16384 + d * 128 + o]);
  } else if (bid < CB + TB + HB) {
    int i = (bid - CB - TB) * 256 + threadIdx.x;
    if (i >= E) return;
    atomicAdd(&cnt[tgt[i]], 1);
    atomicAdd(&cnt[src[i]], 1);
  } else {
    __shared__ int nz_off, big;
    if (threadIdx.x == 0) { nz_off = 0; big = 0; }
    __syncthreads();
    int lnz = 0, lbig = 0;
    for (int i = threadIdx.x; i < mbytes; i += 256) {
      unsigned char v = mask[i];
      if ((i & 3) && v) lnz++;
      if (v > 1) lbig++;
    }
    if (lnz) atomicAdd(&nz_off, lnz);
    if (lbig) atomicAdd(&big, lbig);
    __syncthreads();
    if (threadIdx.x == 0) *flag_out = (nz_off == 0) ? 0 : ((big == 0) ? 1 : 2);
  }
}

// ---------------- S2a: per-block sums ----------------
__global__ __launch_bounds__(256) void scan1_kernel(const int* __restrict__ cnt, int N,
                                                    int* __restrict__ bsum) {
  __shared__ int s[256];
  int t = threadIdx.x, i = blockIdx.x * 256 + t;
  s[t] = (i < N) ? cnt[i] : 0;
  __syncthreads();
#pragma unroll
  for (int off = 128; off > 0; off >>= 1) {
    if (t < off) s[t] += s[t + off];
    __syncthreads();
  }
  if (t == 0) bsum[blockIdx.x] = s[0];
}

// ---------------- S2b: scan block sums (nb <= 512) ----------------
__global__ void scan2_kernel(const int* __restrict__ bsum, int nb,
                             int* __restrict__ bexcl, int* __restrict__ base, int N) {
  __shared__ int s[512];
  int t = threadIdx.x;
  int v = (t < nb) ? bsum[t] : 0;
  s[t] = v;
  __syncthreads();
  for (int off = 1; off < 512; off <<= 1) {
    int x = (t >= off) ? s[t - off] : 0;
    __syncthreads();
    s[t] += x;
    __syncthreads();
  }
  if (t < nb) bexcl[t] = s[t] - v;
  if (t == nb - 1) base[N] = s[t];
}

// ---------------- S2c: per-element exclusive base + cursor ----------------
__global__ __launch_bounds__(256) void scan3_kernel(const int* __restrict__ cnt, int N,
                                                    const int* __restrict__ bexcl,
                                                    int* __restrict__ base,
                                                    int* __restrict__ cursor) {
  __shared__ int s[256];
  int t = threadIdx.x, i = blockIdx.x * 256 + t;
  int c = (i < N) ? cnt[i] : 0;
  s[t] = c;
  __syncthreads();
  for (int off = 1; off < 256; off <<= 1) {
    int x = (t >= off) ? s[t - off] : 0;
    __syncthreads();
    s[t] += x;
    __syncthreads();
  }
  if (i < N) {
    int v = bexcl[blockIdx.x] + s[t] - c;
    base[i] = v;
    cursor[i] = v;
  }
}

// ---------------- S3: scatter messages; coeffs pre-multiplied w*c[r,b] -> 8 bf16 ----------------
__global__ __launch_bounds__(256) void scatter_kernel(const int* __restrict__ src,
                                                      const int* __restrict__ tgt,
                                                      const int* __restrict__ et,
                                                      const float* __restrict__ ew, int E,
                                                      const float* __restrict__ rbw,
                                                      int* __restrict__ cursor,
                                                      unsigned* __restrict__ msrc,
                                                      uint4* __restrict__ mcoef) {
  __shared__ float ctab[264];
  for (int i = threadIdx.x; i < 264; i += 256) ctab[i] = rbw[i];
  __syncthreads();
  int i = blockIdx.x * 256 + threadIdx.x;
  if (i >= E) return;
  int s = src[i], g = tgt[i], r = et[i];
  float w = ew[i];
  uint4 cv;
  {
    const float* c = &ctab[r * 8];
    cv.x = (unsigned)f2bf(w * c[0]) | ((unsigned)f2bf(w * c[1]) << 16);
    cv.y = (unsigned)f2bf(w * c[2]) | ((unsigned)f2bf(w * c[3]) << 16);
    cv.z = (unsigned)f2bf(w * c[4]) | ((unsigned)f2bf(w * c[5]) << 16);
    cv.w = (unsigned)f2bf(w * c[6]) | ((unsigned)f2bf(w * c[7]) << 16);
  }
  int s1 = atomicAdd(&cursor[g], 1);
  msrc[s1] = (unsigned)s;
  mcoef[s1] = cv;
  int s2 = atomicAdd(&cursor[s], 1);
  msrc[s2] = (unsigned)g;
  mcoef[s2] = cv;
}

// ---------------- zero-pad tail of message arrays (8 entries) ----------------
__global__ void pad_kernel(unsigned* __restrict__ msrc, uint4* __restrict__ mcoef, int M) {
  int t = threadIdx.x;
  if (t < 8) {
    msrc[M + t] = 0u;
    mcoef[M + t] = make_uint4(0u, 0u, 0u, 0u);
  }
}

// ---------------- K: per-target gather (scalar meta, 8-deep MLP, pk-fma) + block MFMA ----------------
// block = 512 thr (8 waves), owns 32 target rows; wave owns 4 targets.
// LDS: zs = 32 rows x 1024 k bf16 (XOR-swizzled) = 65536 B
__global__ __launch_bounds__(512, 4) void gather_kernel(
    const unsigned* __restrict__ xb32, const unsigned short* __restrict__ bmt,
    const int* __restrict__ base, const unsigned* __restrict__ msrc,
    const uint4* __restrict__ mcoef, const float* __restrict__ rbw,
    const void* __restrict__ maskp, const int* __restrict__ flag_p,
    float* __restrict__ out, int N) {
  extern __shared__ char smem[];
  int t = threadIdx.x;
  int wid = t >> 6, l = t & 63;
  int t0 = blockIdx.x * 32;
  int flag = *flag_p;  // uniform

  for (int j = 0; j < 4; ++j) {
    int tg = __builtin_amdgcn_readfirstlane(t0 + wid * 4 + j);  // force SGPR
    int tgc = min(tg, N - 1);
    int beg = __builtin_amdgcn_readfirstlane(base[tgc]);
    int cnt = __builtin_amdgcn_readfirstlane(base[tgc + 1]) - beg;
    if (tg >= N) cnt = 0;
    // self-loop seed (f32 coeffs, uniform scalar loads)
    unsigned xs = xb32[(size_t)tgc * 64 + l];
    int keep;
    if (flag == 0)      keep = ((const int*)maskp)[tgc] != 0;
    else if (flag == 1) keep = ((const unsigned char*)maskp)[tgc] != 0;
    else                keep = ((const float*)maskp)[tgc] != 0.f;
    float ms = (keep && tg < N) ? 1.f : 0.f;
    f32x2 xv0 = {__uint_as_float(xs << 16), __uint_as_float(xs & 0xFFFF0000u)};
    f32x2 z[8];
#pragma unroll
    for (int b = 0; b < 8; ++b) {
      float a = ms * rbw[256 + b];
      z[b] = (f32x2){a, a} * xv0;
    }
    for (int mb = 0; mb < cnt; mb += 8) {
      // meta: wave-uniform loads (global tail hits the zero pad; interior tail masked below)
      unsigned rowv[8];
      uint4 cf[8];
#pragma unroll
      for (int s = 0; s < 8; ++s) {
        rowv[s] = msrc[beg + mb + s];
        cf[s] = mcoef[beg + mb + s];
      }
      // 8 independent x-row loads (SGPR base + lane offset)
      unsigned xr[8];
#pragma unroll
      for (int s = 0; s < 8; ++s) xr[s] = xb32[(size_t)rowv[s] * 64 + l];
      // FMA: 8 pk-fma per message; coeff unpack + validity mask on scalar pipe
#pragma unroll
      for (int s = 0; s < 8; ++s) {
        unsigned vm = ((mb + s) < cnt) ? 0xFFFFFFFFu : 0u;  // wave-uniform SALU select
        f32x2 xv = {__uint_as_float(xr[s] << 16), __uint_as_float(xr[s] & 0xFFFF0000u)};
        unsigned cw[4] = {cf[s].x & vm, cf[s].y & vm, cf[s].z & vm, cf[s].w & vm};
#pragma unroll
        for (int q = 0; q < 4; ++q) {
          float a0 = __uint_as_float(cw[q] << 16);
          float a1 = __uint_as_float(cw[q] & 0xFFFF0000u);
          z[2 * q] = __builtin_elementwise_fma((f32x2){a0, a0}, xv, z[2 * q]);
          z[2 * q + 1] = __builtin_elementwise_fma((f32x2){a1, a1}, xv, z[2 * q + 1]);
        }
      }
    }
    // flush z row to LDS (bf16, XOR swizzle)
    int row = wid * 4 + j;
#pragma unroll
    for (int b = 0; b < 8; ++b) {
      unsigned pk = (unsigned)f2bf(z[b][0]) | ((unsigned)f2bf(z[b][1]) << 16);
      int byte = row * 2048 + ((b * 256 + l * 4) ^ ((row & 7) << 4));
      *(unsigned*)(smem + byte) = pk;
    }
  }
  __syncthreads();

  // MFMA: out[32 x 128] = Z(32 x 1024) @ Bstack(1024 x 128); wave owns 16 cols, 2 row-tiles
  int l15 = l & 15, lk8 = (l >> 4) * 8;
  f32x4 acc[2] = {};
  for (int ks = 0; ks < 32; ++ks) {
    int k0 = ks * 32 + lk8;
    bf16x8 a[2], bb;
#pragma unroll
    for (int rt = 0; rt < 2; ++rt) {
      int tr = rt * 16 + l15;
      int byte = tr * 2048 + ((k0 * 2) ^ ((tr & 7) << 4));
      a[rt] = *(const bf16x8*)(smem + byte);
    }
    int col = wid * 16 + l15;
    bb = *(const bf16x8*)(bmt + (size_t)col * 1024 + k0);
#pragma unroll
    for (int rt = 0; rt < 2; ++rt)
      acc[rt] = __builtin_amdgcn_mfma_f32_16x16x32_bf16(a[rt], bb, acc[rt], 0, 0, 0);
  }
#pragma unroll
  for (int rt = 0; rt < 2; ++rt) {
    int rowb = t0 + rt * 16 + (l >> 4) * 4;
    int col = wid * 16 + l15;
#pragma unroll
    for (int i = 0; i < 4; ++i) {
      int row = rowb + i;
      if (row < N) out[(size_t)row * 128 + col] = acc[rt][i];
    }
  }
}

extern "C" void kernel_launch(void* const* d_in, const int* in_sizes, int n_in,
                              void* d_out, int out_size, void* d_ws, size_t ws_size,
                              hipStream_t stream) {
  const float* x = (const float*)d_in[0];
  const void* mask = d_in[1];
  const int* source = (const int*)d_in[2];
  const int* target = (const int*)d_in[3];
  const int* etype = (const int*)d_in[4];
  const float* eweight = (const float*)d_in[5];
  const float* bases = (const float*)d_in[6];
  const float* rbw = (const float*)d_in[7];
  float* out = (float*)d_out;

  const int N = in_sizes[1];   // mask element count == num nodes
  const int E = in_sizes[2];
  const int M = 2 * E;
  const int NB = (N + 255) / 256;

  // workspace layout (256B aligned)
  char* ws = (char*)d_ws;
  size_t off = 0;
  unsigned short* xb = (unsigned short*)(ws + off); off += (size_t)N * 256;        // bf16 x
  unsigned short* bmt = (unsigned short*)(ws + off); off += 128 * 1024 * 2;        // BmatT
  unsigned* msrc = (unsigned*)(ws + off); off += (size_t)(M + 16) * 4;             // src idx
  uint4* mcoef = (uint4*)(ws + off); off += (size_t)(M + 16) * 16;                 // 8 bf16 coeffs
  int* base = (int*)(ws + off); off += ((size_t)N + 64) * 4;                       // N+1 scan
  int* cursor = (int*)(ws + off); off += ((size_t)N + 64) * 4;
  int* cnt = (int*)(ws + off); off += ((size_t)N + 64) * 4;
  int* bsum = (int*)(ws + off); off += 2048;
  int* bexcl = (int*)(ws + off); off += 2048;
  int* flag = (int*)(ws + off); off += 256;

  hipMemsetAsync(cnt, 0, (size_t)N * 4, stream);
  int total8 = (N * 128) / 8;
  int CB = (total8 + 255) / 256;
  int TB = (128 * 1024 + 255) / 256;
  int HB = (E + 255) / 256;
  prep_kernel<<<CB + TB + HB + 1, 256, 0, stream>>>(x, xb, total8, bases, bmt,
                                                    source, target, E, cnt,
                                                    (const unsigned char*)mask,
                                                    N < 8192 ? N : 8192, flag, CB, TB, HB);
  scan1_kernel<<<NB, 256, 0, stream>>>(cnt, N, bsum);
  scan2_kernel<<<1, 512, 0, stream>>>(bsum, NB, bexcl, base, N);
  scan3_kernel<<<NB, 256, 0, stream>>>(cnt, N, bexcl, base, cursor);
  scatter_kernel<<<(E + 255) / 256, 256, 0, stream>>>(source, target, etype, eweight, E,
                                                      rbw, cursor, msrc, mcoef);
  pad_kernel<<<1, 64, 0, stream>>>(msrc, mcoef, M);
  int gblk = (N + 31) / 32;
  size_t shmem = 65536;
  gather_kernel<<<gblk, 512, shmem, stream>>>((const unsigned*)xb, bmt, base, msrc, mcoef,
                                              rbw, mask, flag, out, N);
}

// Round 10
// 247.372 us; speedup vs baseline: 1.3232x; 1.0103x over previous
//
#include <hip/hip_runtime.h>

typedef __attribute__((ext_vector_type(8))) __bf16 bf16x8;
typedef __attribute__((ext_vector_type(4))) float f32x4;
typedef __attribute__((ext_vector_type(2))) float f32x2;
typedef __attribute__((ext_vector_type(8))) unsigned short ushortx8;

#define MC 384  // max messages staged in LDS per block

__device__ inline unsigned short f2bf(float f) {
  unsigned int u = __float_as_uint(f);
  unsigned int r = (u + 0x7FFFu + ((u >> 16) & 1u)) >> 16;  // RNE
  return (unsigned short)r;
}

// ---------------- prep: fused conv | tconv | hist | detect (block-range dispatch) ----------------
__global__ __launch_bounds__(256) void prep_kernel(const float* __restrict__ x,
                                                   unsigned short* __restrict__ xb, int total8,
                                                   const float* __restrict__ bases,
                                                   unsigned short* __restrict__ bmt,
                                                   const int* __restrict__ src,
                                                   const int* __restrict__ tgt, int E,
                                                   int* __restrict__ cnt,
                                                   const unsigned char* __restrict__ mask,
                                                   int mbytes, int* __restrict__ flag_out,
                                                   int CB, int TB, int HB) {
  int bid = blockIdx.x;
  if (bid < CB) {
    int id = bid * 256 + threadIdx.x;
    if (id >= total8) return;
    f32x4 f0 = ((const f32x4*)x)[2 * id];
    f32x4 f1 = ((const f32x4*)x)[2 * id + 1];
    ushortx8 r;
    r[0] = f2bf(f0[0]); r[1] = f2bf(f0[1]); r[2] = f2bf(f0[2]); r[3] = f2bf(f0[3]);
    r[4] = f2bf(f1[0]); r[5] = f2bf(f1[1]); r[6] = f2bf(f1[2]); r[7] = f2bf(f1[3]);
    ((ushortx8*)xb)[id] = r;
  } else if (bid < CB + TB) {
    int id = (bid - CB) * 256 + threadIdx.x;
    if (id >= 128 * 1024) return;
    int o = id >> 10, k = id & 1023, b = k >> 7, d = k & 127;
    bmt[id] = f2bf(bases[b * 16384 + d * 128 + o]);
  } else if (bid < CB + TB + HB) {
    int i = (bid - CB - TB) * 256 + threadIdx.x;
    if (i >= E) return;
    atomicAdd(&cnt[tgt[i]], 1);
    atomicAdd(&cnt[src[i]], 1);
  } else {
    __shared__ int nz_off, big;
    if (threadIdx.x == 0) { nz_off = 0; big = 0; }
    __syncthreads();
    int lnz = 0, lbig = 0;
    for (int i = threadIdx.x; i < mbytes; i += 256) {
      unsigned char v = mask[i];
      if ((i & 3) && v) lnz++;
      if (v > 1) lbig++;
    }
    if (lnz) atomicAdd(&nz_off, lnz);
    if (lbig) atomicAdd(&big, lbig);
    __syncthreads();
    if (threadIdx.x == 0) *flag_out = (nz_off == 0) ? 0 : ((big == 0) ? 1 : 2);
  }
}

// ---------------- S2a: per-block sums ----------------
__global__ __launch_bounds__(256) void scan1_kernel(const int* __restrict__ cnt, int N,
                                                    int* __restrict__ bsum) {
  __shared__ int s[256];
  int t = threadIdx.x, i = blockIdx.x * 256 + t;
  s[t] = (i < N) ? cnt[i] : 0;
  __syncthreads();
#pragma unroll
  for (int off = 128; off > 0; off >>= 1) {
    if (t < off) s[t] += s[t + off];
    __syncthreads();
  }
  if (t == 0) bsum[blockIdx.x] = s[0];
}

// ---------------- S2b: scan block sums (nb <= 512) ----------------
__global__ void scan2_kernel(const int* __restrict__ bsum, int nb,
                             int* __restrict__ bexcl, int* __restrict__ base, int N) {
  __shared__ int s[512];
  int t = threadIdx.x;
  int v = (t < nb) ? bsum[t] : 0;
  s[t] = v;
  __syncthreads();
  for (int off = 1; off < 512; off <<= 1) {
    int x = (t >= off) ? s[t - off] : 0;
    __syncthreads();
    s[t] += x;
    __syncthreads();
  }
  if (t < nb) bexcl[t] = s[t] - v;
  if (t == nb - 1) base[N] = s[t];
}

// ---------------- S2c: per-element exclusive base + cursor ----------------
__global__ __launch_bounds__(256) void scan3_kernel(const int* __restrict__ cnt, int N,
                                                    const int* __restrict__ bexcl,
                                                    int* __restrict__ base,
                                                    int* __restrict__ cursor) {
  __shared__ int s[256];
  int t = threadIdx.x, i = blockIdx.x * 256 + t;
  int c = (i < N) ? cnt[i] : 0;
  s[t] = c;
  __syncthreads();
  for (int off = 1; off < 256; off <<= 1) {
    int x = (t >= off) ? s[t - off] : 0;
    __syncthreads();
    s[t] += x;
    __syncthreads();
  }
  if (i < N) {
    int v = bexcl[blockIdx.x] + s[t] - c;
    base[i] = v;
    cursor[i] = v;
  }
}

// ---------------- S3: scatter messages; coeffs pre-multiplied w*c[r,b] -> 8 bf16 ----------------
__global__ __launch_bounds__(256) void scatter_kernel(const int* __restrict__ src,
                                                      const int* __restrict__ tgt,
                                                      const int* __restrict__ et,
                                                      const float* __restrict__ ew, int E,
                                                      const float* __restrict__ rbw,
                                                      int* __restrict__ cursor,
                                                      unsigned* __restrict__ msrc,
                                                      uint4* __restrict__ mcoef) {
  __shared__ float ctab[264];
  for (int i = threadIdx.x; i < 264; i += 256) ctab[i] = rbw[i];
  __syncthreads();
  int i = blockIdx.x * 256 + threadIdx.x;
  if (i >= E) return;
  int s = src[i], g = tgt[i], r = et[i];
  float w = ew[i];
  uint4 cv;
  {
    const float* c = &ctab[r * 8];
    cv.x = (unsigned)f2bf(w * c[0]) | ((unsigned)f2bf(w * c[1]) << 16);
    cv.y = (unsigned)f2bf(w * c[2]) | ((unsigned)f2bf(w * c[3]) << 16);
    cv.z = (unsigned)f2bf(w * c[4]) | ((unsigned)f2bf(w * c[5]) << 16);
    cv.w = (unsigned)f2bf(w * c[6]) | ((unsigned)f2bf(w * c[7]) << 16);
  }
  int s1 = atomicAdd(&cursor[g], 1);
  msrc[s1] = (unsigned)s;
  mcoef[s1] = cv;
  int s2 = atomicAdd(&cursor[s], 1);
  msrc[s2] = (unsigned)g;
  mcoef[s2] = cv;
}

// ---------------- zero-pad tail of message arrays (8 entries) ----------------
__global__ void pad_kernel(unsigned* __restrict__ msrc, uint4* __restrict__ mcoef, int M) {
  int t = threadIdx.x;
  if (t < 8) {
    msrc[M + t] = 0u;
    mcoef[M + t] = make_uint4(0u, 0u, 0u, 0u);
  }
}

// ---------------- pair message-processing helpers (meta from LDS or global) ----------------
template <bool LDSM>
__device__ __forceinline__ void load_quad(const unsigned* __restrict__ xb32,
                                          const unsigned* lms,
                                          const unsigned* __restrict__ gms, int B0,
                                          int loc, int mb, int cnt, int l,
                                          unsigned (&xr)[4]) {
  if (mb < cnt) {
#pragma unroll
    for (int s = 0; s < 4; ++s) {
      int lo = loc + mb + s;
      unsigned row = LDSM ? lms[lo] : gms[B0 + lo];
      xr[s] = xb32[(size_t)row * 64 + l];
    }
  }
}

template <bool LDSM>
__device__ __forceinline__ void fma_quad(const uint4* lmc,
                                         const uint4* __restrict__ gmc, int B0,
                                         int loc, int mb, int cnt,
                                         const unsigned (&xr)[4], f32x2 (&z)[8]) {
  if (mb < cnt) {
#pragma unroll
    for (int s = 0; s < 4; ++s) {
      int lo = loc + mb + s;
      uint4 cf = LDSM ? lmc[lo] : gmc[B0 + lo];
      unsigned vm = ((mb + s) < cnt) ? 0xFFFFFFFFu : 0u;
      f32x2 xv = {__uint_as_float(xr[s] << 16), __uint_as_float(xr[s] & 0xFFFF0000u)};
      unsigned c0 = cf.x & vm, c1 = cf.y & vm, c2 = cf.z & vm, c3 = cf.w & vm;
      float a;
      a = __uint_as_float(c0 << 16);          z[0] = __builtin_elementwise_fma((f32x2){a, a}, xv, z[0]);
      a = __uint_as_float(c0 & 0xFFFF0000u);  z[1] = __builtin_elementwise_fma((f32x2){a, a}, xv, z[1]);
      a = __uint_as_float(c1 << 16);          z[2] = __builtin_elementwise_fma((f32x2){a, a}, xv, z[2]);
      a = __uint_as_float(c1 & 0xFFFF0000u);  z[3] = __builtin_elementwise_fma((f32x2){a, a}, xv, z[3]);
      a = __uint_as_float(c2 << 16);          z[4] = __builtin_elementwise_fma((f32x2){a, a}, xv, z[4]);
      a = __uint_as_float(c2 & 0xFFFF0000u);  z[5] = __builtin_elementwise_fma((f32x2){a, a}, xv, z[5]);
      a = __uint_as_float(c3 << 16);          z[6] = __builtin_elementwise_fma((f32x2){a, a}, xv, z[6]);
      a = __uint_as_float(c3 & 0xFFFF0000u);  z[7] = __builtin_elementwise_fma((f32x2){a, a}, xv, z[7]);
    }
  }
}

template <bool LDSM>
__device__ __forceinline__ void do_pair(const unsigned* __restrict__ xb32,
                                        const unsigned* lms, const uint4* lmc,
                                        const unsigned* __restrict__ gms,
                                        const uint4* __restrict__ gmc, int B0,
                                        int locA, int cntA, int locB, int cntB, int l,
                                        f32x2 (&zA)[8], f32x2 (&zB)[8]) {
  int rounds = (max(cntA, cntB) + 3) >> 2;
  if (rounds <= 0) return;
  unsigned xA0[4], xA1[4], xB0[4], xB1[4];
  load_quad<LDSM>(xb32, lms, gms, B0, locA, 0, cntA, l, xA0);
  load_quad<LDSM>(xb32, lms, gms, B0, locB, 0, cntB, l, xB0);
  int r = 0;
  while (true) {
    // even round r: consume buf0, prefetch into buf1
    if (r + 1 < rounds) {
      load_quad<LDSM>(xb32, lms, gms, B0, locA, (r + 1) * 4, cntA, l, xA1);
      load_quad<LDSM>(xb32, lms, gms, B0, locB, (r + 1) * 4, cntB, l, xB1);
    }
    fma_quad<LDSM>(lmc, gmc, B0, locA, r * 4, cntA, xA0, zA);
    fma_quad<LDSM>(lmc, gmc, B0, locB, r * 4, cntB, xB0, zB);
    if (++r >= rounds) break;
    // odd round r: consume buf1, prefetch into buf0
    if (r + 1 < rounds) {
      load_quad<LDSM>(xb32, lms, gms, B0, locA, (r + 1) * 4, cntA, l, xA0);
      load_quad<LDSM>(xb32, lms, gms, B0, locB, (r + 1) * 4, cntB, l, xB0);
    }
    fma_quad<LDSM>(lmc, gmc, B0, locA, r * 4, cntA, xA1, zA);
    fma_quad<LDSM>(lmc, gmc, B0, locB, r * 4, cntB, xB1, zB);
    if (++r >= rounds) break;
  }
}

// ---------------- K: block-staged meta + paired 4-deep dbuf gather + block MFMA ----------------
// block = 512 thr (8 waves), owns 32 targets (contiguous message span); wave owns 4 targets (2 pairs).
// LDS: z 32x2048B (65536) | lms u32[MC] (1536) | lmc uint4[MC] (6144) | lbase int[33]
__global__ __launch_bounds__(512, 4) void gather_kernel(
    const unsigned* __restrict__ xb32, const unsigned short* __restrict__ bmt,
    const int* __restrict__ base, const unsigned* __restrict__ msrc,
    const uint4* __restrict__ mcoef, const float* __restrict__ rbw,
    const void* __restrict__ maskp, const int* __restrict__ flag_p,
    float* __restrict__ out, int N) {
  extern __shared__ char smem[];
  unsigned* lms = (unsigned*)(smem + 65536);
  uint4* lmc = (uint4*)(smem + 65536 + 1536);
  int* lbase = (int*)(smem + 65536 + 1536 + 6144);
  int t = threadIdx.x;
  int wid = t >> 6, l = t & 63;
  int t0 = blockIdx.x * 32;
  int flag = *flag_p;  // uniform

  // cooperative staging: base slice + message metadata
  if (t < 33) lbase[t] = base[min(t0 + t, N)];
  int B0 = __builtin_amdgcn_readfirstlane(base[min(t0, N)]);
  int B1 = __builtin_amdgcn_readfirstlane(base[min(t0 + 32, N)]);
  int nm = B1 - B0;
  bool use_lds = (nm <= MC);
  if (use_lds) {
    for (int i = t; i < nm; i += 512) {
      lms[i] = msrc[B0 + i];
      lmc[i] = mcoef[B0 + i];
    }
    if (t < 8 && nm + t < MC) {
      lms[nm + t] = 0u;
      lmc[nm + t] = make_uint4(0u, 0u, 0u, 0u);
    }
  }
  __syncthreads();

  for (int p = 0; p < 2; ++p) {
    int jA = wid * 4 + p * 2, jB = jA + 1;
    int tgA = t0 + jA, tgB = t0 + jB;
    int tcA = min(tgA, N - 1), tcB = min(tgB, N - 1);
    int begA = __builtin_amdgcn_readfirstlane(lbase[jA]);
    int begB = __builtin_amdgcn_readfirstlane(lbase[jB]);
    int endB = __builtin_amdgcn_readfirstlane(lbase[jB + 1]);
    int cntA = (tgA < N) ? (begB - begA) : 0;
    int cntB = (tgB < N) ? (endB - begB) : 0;
    int locA = begA - B0, locB = begB - B0;
    // self-loop seeds (issued before message rounds)
    unsigned xsA = xb32[(size_t)tcA * 64 + l];
    unsigned xsB = xb32[(size_t)tcB * 64 + l];
    int keepA, keepB;
    if (flag == 0) {
      keepA = ((const int*)maskp)[tcA] != 0; keepB = ((const int*)maskp)[tcB] != 0;
    } else if (flag == 1) {
      keepA = ((const unsigned char*)maskp)[tcA] != 0; keepB = ((const unsigned char*)maskp)[tcB] != 0;
    } else {
      keepA = ((const float*)maskp)[tcA] != 0.f; keepB = ((const float*)maskp)[tcB] != 0.f;
    }
    float msA = (keepA && tgA < N) ? 1.f : 0.f;
    float msB = (keepB && tgB < N) ? 1.f : 0.f;
    f32x2 zA[8], zB[8];
    f32x2 xvA = {__uint_as_float(xsA << 16), __uint_as_float(xsA & 0xFFFF0000u)};
    f32x2 xvB = {__uint_as_float(xsB << 16), __uint_as_float(xsB & 0xFFFF0000u)};
#pragma unroll
    for (int b = 0; b < 8; ++b) {
      float cb = rbw[256 + b];  // uniform
      float aA = msA * cb, aB = msB * cb;
      zA[b] = (f32x2){aA, aA} * xvA;
      zB[b] = (f32x2){aB, aB} * xvB;
    }
    if (use_lds)
      do_pair<true>(xb32, lms, lmc, msrc, mcoef, B0, locA, cntA, locB, cntB, l, zA, zB);
    else
      do_pair<false>(xb32, lms, lmc, msrc, mcoef, B0, locA, cntA, locB, cntB, l, zA, zB);
    // flush both rows to LDS (bf16, XOR swizzle)
#pragma unroll
    for (int b = 0; b < 8; ++b) {
      unsigned pkA = (unsigned)f2bf(zA[b][0]) | ((unsigned)f2bf(zA[b][1]) << 16);
      unsigned pkB = (unsigned)f2bf(zB[b][0]) | ((unsigned)f2bf(zB[b][1]) << 16);
      int byA = jA * 2048 + ((b * 256 + l * 4) ^ ((jA & 7) << 4));
      int byB = jB * 2048 + ((b * 256 + l * 4) ^ ((jB & 7) << 4));
      *(unsigned*)(smem + byA) = pkA;
      *(unsigned*)(smem + byB) = pkB;
    }
  }
  __syncthreads();

  // MFMA: out[32 x 128] = Z(32 x 1024) @ Bstack(1024 x 128); wave owns 16 cols, 2 row-tiles
  int l15 = l & 15, lk8 = (l >> 4) * 8;
  f32x4 acc[2] = {};
  for (int ks = 0; ks < 32; ++ks) {
    int k0 = ks * 32 + lk8;
    bf16x8 a[2], bb;
#pragma unroll
    for (int rt = 0; rt < 2; ++rt) {
      int tr = rt * 16 + l15;
      int byte = tr * 2048 + ((k0 * 2) ^ ((tr & 7) << 4));
      a[rt] = *(const bf16x8*)(smem + byte);
    }
    int col = wid * 16 + l15;
    bb = *(const bf16x8*)(bmt + (size_t)col * 1024 + k0);
#pragma unroll
    for (int rt = 0; rt < 2; ++rt)
      acc[rt] = __builtin_amdgcn_mfma_f32_16x16x32_bf16(a[rt], bb, acc[rt], 0, 0, 0);
  }
#pragma unroll
  for (int rt = 0; rt < 2; ++rt) {
    int rowb = t0 + rt * 16 + (l >> 4) * 4;
    int col = wid * 16 + l15;
#pragma unroll
    for (int i = 0; i < 4; ++i) {
      int row = rowb + i;
      if (row < N) out[(size_t)row * 128 + col] = acc[rt][i];
    }
  }
}

extern "C" void kernel_launch(void* const* d_in, const int* in_sizes, int n_in,
                              void* d_out, int out_size, void* d_ws, size_t ws_size,
                              hipStream_t stream) {
  const float* x = (const float*)d_in[0];
  const void* mask = d_in[1];
  const int* source = (const int*)d_in[2];
  const int* target = (const int*)d_in[3];
  const int* etype = (const int*)d_in[4];
  const float* eweight = (const float*)d_in[5];
  const float* bases = (const float*)d_in[6];
  const float* rbw = (const float*)d_in[7];
  float* out = (float*)d_out;

  const int N = in_sizes[1];   // mask element count == num nodes
  const int E = in_sizes[2];
  const int M = 2 * E;
  const int NB = (N + 255) / 256;

  // workspace layout (256B aligned)
  char* ws = (char*)d_ws;
  size_t off = 0;
  unsigned short* xb = (unsigned short*)(ws + off); off += (size_t)N * 256;        // bf16 x
  unsigned short* bmt = (unsigned short*)(ws + off); off += 128 * 1024 * 2;        // BmatT
  unsigned* msrc = (unsigned*)(ws + off); off += (size_t)(M + 16) * 4;             // src idx
  uint4* mcoef = (uint4*)(ws + off); off += (size_t)(M + 16) * 16;                 // 8 bf16 coeffs
  int* base = (int*)(ws + off); off += ((size_t)N + 64) * 4;                       // N+1 scan
  int* cursor = (int*)(ws + off); off += ((size_t)N + 64) * 4;
  int* cnt = (int*)(ws + off); off += ((size_t)N + 64) * 4;
  int* bsum = (int*)(ws + off); off += 2048;
  int* bexcl = (int*)(ws + off); off += 2048;
  int* flag = (int*)(ws + off); off += 256;

  hipMemsetAsync(cnt, 0, (size_t)N * 4, stream);
  int total8 = (N * 128) / 8;
  int CB = (total8 + 255) / 256;
  int TB = (128 * 1024 + 255) / 256;
  int HB = (E + 255) / 256;
  prep_kernel<<<CB + TB + HB + 1, 256, 0, stream>>>(x, xb, total8, bases, bmt,
                                                    source, target, E, cnt,
                                                    (const unsigned char*)mask,
                                                    N < 8192 ? N : 8192, flag, CB, TB, HB);
  scan1_kernel<<<NB, 256, 0, stream>>>(cnt, N, bsum);
  scan2_kernel<<<1, 512, 0, stream>>>(bsum, NB, bexcl, base, N);
  scan3_kernel<<<NB, 256, 0, stream>>>(cnt, N, bexcl, base, cursor);
  scatter_kernel<<<(E + 255) / 256, 256, 0, stream>>>(source, target, etype, eweight, E,
                                                      rbw, cursor, msrc, mcoef);
  pad_kernel<<<1, 64, 0, stream>>>(msrc, mcoef, M);
  int gblk = (N + 31) / 32;
  size_t shmem = 65536 + 1536 + 6144 + 136;
  gather_kernel<<<gblk, 512, shmem, stream>>>((const unsigned*)xb, bmt, base, msrc, mcoef,
                                              rbw, mask, flag, out, N);
}

// Round 11
// 236.640 us; speedup vs baseline: 1.3832x; 1.0454x over previous
//
#include <hip/hip_runtime.h>

typedef __attribute__((ext_vector_type(8))) __bf16 bf16x8;
typedef __attribute__((ext_vector_type(4))) float f32x4;
typedef __attribute__((ext_vector_type(8))) unsigned short ushortx8;

#define MC 384   // max messages staged in LDS per block
#define MCP 448  // MC + 64 overrun pad

__device__ inline unsigned short f2bf(float f) {
  unsigned int u = __float_as_uint(f);
  unsigned int r = (u + 0x7FFFu + ((u >> 16) & 1u)) >> 16;  // RNE
  return (unsigned short)r;
}
__device__ inline float bflo(unsigned u) { return __uint_as_float(u << 16); }
__device__ inline float bfhi(unsigned u) { return __uint_as_float(u & 0xFFFF0000u); }

// ---------------- prep: fused conv | tconv | hist | detect (block-range dispatch) ----------------
__global__ __launch_bounds__(256) void prep_kernel(const float* __restrict__ x,
                                                   unsigned short* __restrict__ xb, int total8,
                                                   const float* __restrict__ bases,
                                                   unsigned short* __restrict__ bmt,
                                                   const int* __restrict__ src,
                                                   const int* __restrict__ tgt, int E,
                                                   int* __restrict__ cnt,
                                                   const unsigned char* __restrict__ mask,
                                                   int mbytes, int* __restrict__ flag_out,
                                                   int CB, int TB, int HB) {
  int bid = blockIdx.x;
  if (bid < CB) {
    int id = bid * 256 + threadIdx.x;
    if (id >= total8) return;
    f32x4 f0 = ((const f32x4*)x)[2 * id];
    f32x4 f1 = ((const f32x4*)x)[2 * id + 1];
    ushortx8 r;
    r[0] = f2bf(f0[0]); r[1] = f2bf(f0[1]); r[2] = f2bf(f0[2]); r[3] = f2bf(f0[3]);
    r[4] = f2bf(f1[0]); r[5] = f2bf(f1[1]); r[6] = f2bf(f1[2]); r[7] = f2bf(f1[3]);
    ((ushortx8*)xb)[id] = r;
  } else if (bid < CB + TB) {
    int id = (bid - CB) * 256 + threadIdx.x;
    if (id >= 128 * 1024) return;
    int o = id >> 10, k = id & 1023, b = k >> 7, d = k & 127;
    bmt[id] = f2bf(bases[b * 16384 + d * 128 + o]);
  } else if (bid < CB + TB + HB) {
    int i = (bid - CB - TB) * 256 + threadIdx.x;
    if (i >= E) return;
    atomicAdd(&cnt[tgt[i]], 1);
    atomicAdd(&cnt[src[i]], 1);
  } else {
    __shared__ int nz_off, big;
    if (threadIdx.x == 0) { nz_off = 0; big = 0; }
    __syncthreads();
    int lnz = 0, lbig = 0;
    for (int i = threadIdx.x; i < mbytes; i += 256) {
      unsigned char v = mask[i];
      if ((i & 3) && v) lnz++;
      if (v > 1) lbig++;
    }
    if (lnz) atomicAdd(&nz_off, lnz);
    if (lbig) atomicAdd(&big, lbig);
    __syncthreads();
    if (threadIdx.x == 0) *flag_out = (nz_off == 0) ? 0 : ((big == 0) ? 1 : 2);
  }
}

// ---------------- scanA: per-block sums ----------------
__global__ __launch_bounds__(256) void scanA_kernel(const int* __restrict__ cnt, int N,
                                                    int* __restrict__ bsum) {
  __shared__ int s[256];
  int t = threadIdx.x, i = blockIdx.x * 256 + t;
  s[t] = (i < N) ? cnt[i] : 0;
  __syncthreads();
#pragma unroll
  for (int off = 128; off > 0; off >>= 1) {
    if (t < off) s[t] += s[t + off];
    __syncthreads();
  }
  if (t == 0) bsum[blockIdx.x] = s[0];
}

// ---------------- scanB: fused block-prefix + per-element exclusive scan + cursor ----------------
__global__ __launch_bounds__(256) void scanB_kernel(const int* __restrict__ cnt, int N,
                                                    const int* __restrict__ bsum, int NB,
                                                    int* __restrict__ base,
                                                    int* __restrict__ cursor) {
  __shared__ int s[256];
  __shared__ int spref;
  int t = threadIdx.x, bid = blockIdx.x;
  // prefix of bsum[0..bid)
  int acc = 0;
  for (int i = t; i < bid; i += 256) acc += bsum[i];
  s[t] = acc;
  __syncthreads();
#pragma unroll
  for (int off = 128; off > 0; off >>= 1) {
    if (t < off) s[t] += s[t + off];
    __syncthreads();
  }
  if (t == 0) spref = s[0];
  __syncthreads();
  int pref = spref;
  __syncthreads();
  int i = bid * 256 + t;
  int c = (i < N) ? cnt[i] : 0;
  s[t] = c;
  __syncthreads();
  for (int off = 1; off < 256; off <<= 1) {
    int x = (t >= off) ? s[t - off] : 0;
    __syncthreads();
    s[t] += x;
    __syncthreads();
  }
  if (i < N) {
    int v = pref + s[t] - c;
    base[i] = v;
    cursor[i] = v;
  }
  if (bid == NB - 1 && t == 255) base[N] = pref + s[255];
}

// ---------------- scatter: messages (src) + premultiplied bf16 coeffs; pad folded in ----------------
__global__ __launch_bounds__(256) void scatter_kernel(const int* __restrict__ src,
                                                      const int* __restrict__ tgt,
                                                      const int* __restrict__ et,
                                                      const float* __restrict__ ew, int E,
                                                      const float* __restrict__ rbw,
                                                      int* __restrict__ cursor,
                                                      unsigned* __restrict__ msrc,
                                                      uint4* __restrict__ mcoef) {
  __shared__ float ctab[264];
  for (int i = threadIdx.x; i < 264; i += 256) ctab[i] = rbw[i];
  __syncthreads();
  if (blockIdx.x == 0 && threadIdx.x < 80) {  // zero pad tail (overrun region)
    msrc[2 * E + threadIdx.x] = 0u;
    mcoef[2 * E + threadIdx.x] = make_uint4(0u, 0u, 0u, 0u);
  }
  int i = blockIdx.x * 256 + threadIdx.x;
  if (i >= E) return;
  int s = src[i], g = tgt[i], r = et[i];
  float w = ew[i];
  uint4 cv;
  {
    const float* c = &ctab[r * 8];
    cv.x = (unsigned)f2bf(w * c[0]) | ((unsigned)f2bf(w * c[1]) << 16);
    cv.y = (unsigned)f2bf(w * c[2]) | ((unsigned)f2bf(w * c[3]) << 16);
    cv.z = (unsigned)f2bf(w * c[4]) | ((unsigned)f2bf(w * c[5]) << 16);
    cv.w = (unsigned)f2bf(w * c[6]) | ((unsigned)f2bf(w * c[7]) << 16);
  }
  int s1 = atomicAdd(&cursor[g], 1);
  msrc[s1] = (unsigned)s;
  mcoef[s1] = cv;
  int s2 = atomicAdd(&cursor[s], 1);
  msrc[s2] = (unsigned)g;
  mcoef[s2] = cv;
}

// ---------------- half-wave duo message loop (2 rows per load instruction) ----------------
template <bool LDSM>
__device__ __forceinline__ void load4(const uint2* __restrict__ xb64,
                                      const unsigned* lms, const unsigned* __restrict__ gms,
                                      int B0, int gcap, int locS, int mb, int ll,
                                      unsigned Nm1, uint2 (&xq)[4]) {
#pragma unroll
  for (int s = 0; s < 4; ++s) {
    int idx = locS + mb + s;
    unsigned row;
    if (LDSM) row = lms[min(idx, MCP - 1)];
    else      row = gms[min(B0 + idx, gcap)];
    row = min(row & 0xFFFFFu, Nm1);
    xq[s] = xb64[(size_t)row * 32 + ll];
  }
}

template <bool LDSM>
__device__ __forceinline__ void fma4(const uint4* lmc, const uint4* __restrict__ gmc,
                                     int B0, int gcap, int locS, int cntS, int mb,
                                     const uint2 (&xq)[4], f32x4 (&z)[8]) {
#pragma unroll
  for (int s = 0; s < 4; ++s) {
    int idx = locS + mb + s;
    uint4 cf;
    if (LDSM) cf = lmc[min(idx, MCP - 1)];
    else      cf = gmc[min(B0 + idx, gcap)];
    unsigned vm = ((mb + s) < cntS) ? 0xFFFFFFFFu : 0u;
    unsigned c0 = cf.x & vm, c1 = cf.y & vm, c2 = cf.z & vm, c3 = cf.w & vm;
    f32x4 xv = {bflo(xq[s].x), bfhi(xq[s].x), bflo(xq[s].y), bfhi(xq[s].y)};
    float a;
    a = bflo(c0); z[0] = __builtin_elementwise_fma((f32x4){a, a, a, a}, xv, z[0]);
    a = bfhi(c0); z[1] = __builtin_elementwise_fma((f32x4){a, a, a, a}, xv, z[1]);
    a = bflo(c1); z[2] = __builtin_elementwise_fma((f32x4){a, a, a, a}, xv, z[2]);
    a = bfhi(c1); z[3] = __builtin_elementwise_fma((f32x4){a, a, a, a}, xv, z[3]);
    a = bflo(c2); z[4] = __builtin_elementwise_fma((f32x4){a, a, a, a}, xv, z[4]);
    a = bfhi(c2); z[5] = __builtin_elementwise_fma((f32x4){a, a, a, a}, xv, z[5]);
    a = bflo(c3); z[6] = __builtin_elementwise_fma((f32x4){a, a, a, a}, xv, z[6]);
    a = bfhi(c3); z[7] = __builtin_elementwise_fma((f32x4){a, a, a, a}, xv, z[7]);
  }
}

template <bool LDSM>
__device__ __forceinline__ void duo_loop(const uint2* __restrict__ xb64,
                                         const unsigned* lms, const uint4* lmc,
                                         const unsigned* __restrict__ gms,
                                         const uint4* __restrict__ gmc,
                                         int B0, int gcap, int locS, int cntS, int rmax,
                                         int ll, unsigned Nm1, f32x4 (&z)[8]) {
  int rounds = (rmax + 3) >> 2;
  if (rounds <= 0) return;
  uint2 xq0[4], xq1[4];
  load4<LDSM>(xb64, lms, gms, B0, gcap, locS, 0, ll, Nm1, xq0);
  for (int r = 0; r < rounds; ++r) {
    if ((r & 1) == 0) {
      if (r + 1 < rounds) load4<LDSM>(xb64, lms, gms, B0, gcap, locS, (r + 1) * 4, ll, Nm1, xq1);
      fma4<LDSM>(lmc, gmc, B0, gcap, locS, cntS, r * 4, xq0, z);
    } else {
      if (r + 1 < rounds) load4<LDSM>(xb64, lms, gms, B0, gcap, locS, (r + 1) * 4, ll, Nm1, xq0);
      fma4<LDSM>(lmc, gmc, B0, gcap, locS, cntS, r * 4, xq1, z);
    }
  }
}

// ---------------- K: block-staged meta + half-wave dwordx2 gather + block MFMA ----------------
// block = 512 thr (8 waves), owns 32 targets; wave owns 4 targets as 2 duos (A,B per half-wave).
// LDS: z 32x2048B (65536) | lms u32[MCP] | lmc uint4[MCP] | lbase int[33]
__global__ __launch_bounds__(512, 4) void gather_kernel(
    const uint2* __restrict__ xb64, const unsigned short* __restrict__ bmt,
    const int* __restrict__ base, const unsigned* __restrict__ msrc,
    const uint4* __restrict__ mcoef, const float* __restrict__ rbw,
    const void* __restrict__ maskp, const int* __restrict__ flag_p,
    float* __restrict__ out, int N, int gcap) {
  extern __shared__ char smem[];
  unsigned* lms = (unsigned*)(smem + 65536);
  uint4* lmc = (uint4*)(smem + 65536 + MCP * 4);
  int* lbase = (int*)(smem + 65536 + MCP * 4 + MCP * 16);
  int t = threadIdx.x;
  int wid = t >> 6, l = t & 63;
  int hw = l >> 5, ll = l & 31;
  int t0 = blockIdx.x * 32;
  int flag = *flag_p;  // uniform
  unsigned Nm1 = (unsigned)(N - 1);

  if (t < 33) lbase[t] = base[min(t0 + t, N)];
  int B0 = __builtin_amdgcn_readfirstlane(base[min(t0, N)]);
  int B1 = __builtin_amdgcn_readfirstlane(base[min(t0 + 32, N)]);
  int nm = B1 - B0;
  bool use_lds = (nm <= MC);
  if (use_lds) {
    for (int i = t; i < nm; i += 512) {
      lms[i] = msrc[B0 + i];
      lmc[i] = mcoef[B0 + i];
    }
    int pz = nm + t;
    if (t < 64 && pz < MCP) {
      lms[pz] = 0u;
      lmc[pz] = make_uint4(0u, 0u, 0u, 0u);
    }
  }
  __syncthreads();

  for (int p = 0; p < 2; ++p) {
    int jA = wid * 4 + p * 2, jB = jA + 1;
    int tgA = t0 + jA, tgB = t0 + jB;
    int begA = __builtin_amdgcn_readfirstlane(lbase[jA]);
    int begB = __builtin_amdgcn_readfirstlane(lbase[jB]);
    int endB = __builtin_amdgcn_readfirstlane(lbase[jB + 1]);
    int cntA = (tgA < N) ? (begB - begA) : 0;
    int cntB = (tgB < N) ? (endB - begB) : 0;
    int locA = begA - B0, locB = begB - B0;
    // per-half selections
    int tgS = hw ? tgB : tgA;
    int tcS = min(tgS, N - 1);
    int locS = hw ? locB : locA;
    int cntS = hw ? cntB : cntA;
    // self-loop seed
    uint2 xs = xb64[(size_t)tcS * 32 + ll];
    int keep;
    if (flag == 0)      keep = ((const int*)maskp)[tcS] != 0;
    else if (flag == 1) keep = ((const unsigned char*)maskp)[tcS] != 0;
    else                keep = ((const float*)maskp)[tcS] != 0.f;
    float ms = (keep && tgS < N) ? 1.f : 0.f;
    f32x4 xv0 = {bflo(xs.x), bfhi(xs.x), bflo(xs.y), bfhi(xs.y)};
    f32x4 z[8];
#pragma unroll
    for (int b = 0; b < 8; ++b) {
      float a = ms * rbw[256 + b];  // uniform scalar load
      z[b] = (f32x4){a, a, a, a} * xv0;
    }
    int rmax = max(cntA, cntB);
    if (use_lds)
      duo_loop<true>(xb64, lms, lmc, msrc, mcoef, B0, gcap, locS, cntS, rmax, ll, Nm1, z);
    else
      duo_loop<false>(xb64, lms, lmc, msrc, mcoef, B0, gcap, locS, cntS, rmax, ll, Nm1, z);
    // flush z row to LDS (bf16, XOR swizzle); lane covers dims 4*ll..4*ll+3 of its target
    int rowS = hw ? jB : jA;
#pragma unroll
    for (int b = 0; b < 8; ++b) {
      unsigned d0 = (unsigned)f2bf(z[b][0]) | ((unsigned)f2bf(z[b][1]) << 16);
      unsigned d1 = (unsigned)f2bf(z[b][2]) | ((unsigned)f2bf(z[b][3]) << 16);
      int byte = rowS * 2048 + ((b * 256 + ll * 8) ^ ((rowS & 7) << 4));
      *(uint2*)(smem + byte) = make_uint2(d0, d1);
    }
  }
  __syncthreads();

  // MFMA: out[32 x 128] = Z(32 x 1024) @ Bstack(1024 x 128); wave owns 16 cols, 2 row-tiles
  int l15 = l & 15, lk8 = (l >> 4) * 8;
  f32x4 acc[2] = {};
  for (int ks = 0; ks < 32; ++ks) {
    int k0 = ks * 32 + lk8;
    bf16x8 a[2], bb;
#pragma unroll
    for (int rt = 0; rt < 2; ++rt) {
      int tr = rt * 16 + l15;
      int byte = tr * 2048 + ((k0 * 2) ^ ((tr & 7) << 4));
      a[rt] = *(const bf16x8*)(smem + byte);
    }
    int col = wid * 16 + l15;
    bb = *(const bf16x8*)(bmt + (size_t)col * 1024 + k0);
#pragma unroll
    for (int rt = 0; rt < 2; ++rt)
      acc[rt] = __builtin_amdgcn_mfma_f32_16x16x32_bf16(a[rt], bb, acc[rt], 0, 0, 0);
  }
#pragma unroll
  for (int rt = 0; rt < 2; ++rt) {
    int rowb = t0 + rt * 16 + (l >> 4) * 4;
    int col = wid * 16 + l15;
#pragma unroll
    for (int i = 0; i < 4; ++i) {
      int row = rowb + i;
      if (row < N) out[(size_t)row * 128 + col] = acc[rt][i];
    }
  }
}

extern "C" void kernel_launch(void* const* d_in, const int* in_sizes, int n_in,
                              void* d_out, int out_size, void* d_ws, size_t ws_size,
                              hipStream_t stream) {
  const float* x = (const float*)d_in[0];
  const void* mask = d_in[1];
  const int* source = (const int*)d_in[2];
  const int* target = (const int*)d_in[3];
  const int* etype = (const int*)d_in[4];
  const float* eweight = (const float*)d_in[5];
  const float* bases = (const float*)d_in[6];
  const float* rbw = (const float*)d_in[7];
  float* out = (float*)d_out;

  const int N = in_sizes[1];   // mask element count == num nodes
  const int E = in_sizes[2];
  const int M = 2 * E;
  const int NB = (N + 255) / 256;

  // workspace layout (256B aligned)
  char* ws = (char*)d_ws;
  size_t off = 0;
  unsigned short* xb = (unsigned short*)(ws + off); off += (size_t)N * 256;        // bf16 x
  unsigned short* bmt = (unsigned short*)(ws + off); off += 128 * 1024 * 2;        // BmatT
  unsigned* msrc = (unsigned*)(ws + off); off += (size_t)(M + 96) * 4;             // src idx
  uint4* mcoef = (uint4*)(ws + off); off += (size_t)(M + 96) * 16;                 // 8 bf16 coeffs
  int* base = (int*)(ws + off); off += ((size_t)N + 64) * 4;                       // N+1 scan
  int* cursor = (int*)(ws + off); off += ((size_t)N + 64) * 4;
  int* cnt = (int*)(ws + off); off += ((size_t)N + 64) * 4;
  int* bsum = (int*)(ws + off); off += 2048;
  int* flag = (int*)(ws + off); off += 256;

  hipMemsetAsync(cnt, 0, (size_t)N * 4, stream);
  int total8 = (N * 128) / 8;
  int CB = (total8 + 255) / 256;
  int TB = (128 * 1024 + 255) / 256;
  int HB = (E + 255) / 256;
  prep_kernel<<<CB + TB + HB + 1, 256, 0, stream>>>(x, xb, total8, bases, bmt,
                                                    source, target, E, cnt,
                                                    (const unsigned char*)mask,
                                                    N < 8192 ? N : 8192, flag, CB, TB, HB);
  scanA_kernel<<<NB, 256, 0, stream>>>(cnt, N, bsum);
  scanB_kernel<<<NB, 256, 0, stream>>>(cnt, N, bsum, NB, base, cursor);
  scatter_kernel<<<(E + 255) / 256, 256, 0, stream>>>(source, target, etype, eweight, E,
                                                      rbw, cursor, msrc, mcoef);
  int gblk = (N + 31) / 32;
  size_t shmem = 65536 + MCP * 4 + MCP * 16 + 136;
  gather_kernel<<<gblk, 512, shmem, stream>>>((const uint2*)xb, bmt, base, msrc, mcoef,
                                              rbw, mask, flag, out, N, M + 79);
}